// Round 2
// baseline (66.927 us; speedup 1.0000x reference)
//
#include <hip/hip_runtime.h>

// GraphSearchPolicy fused kernel for MI355X (gfx950).
// B=2048, A=256, DE=128, DH=256, DR=128, DIN=512, ACT=256, NR=1000.
// One block = 4 batch rows, 256 threads (4 waves). Grid = B/4 = 512 blocks.
// W1/W2 are consumed through a double-buffered LDS pipeline fed by
// global_load_lds (16B/lane), with counted vmcnt waits + raw s_barrier so
// next-tile loads stay in flight across the barrier.

#define BB   4      // batch rows per block
#define DE   128
#define DH   256
#define DR   128
#define DIN  512    // DE + DH + DR
#define ACT  256    // hidden width
#define AA   256    // action-space width
#define KT   32     // K-tile for W staging
#define NT1  (DIN / KT)   // 16 tiles for W1
#define NT2  (ACT / KT)   // 8 tiles for W2

__device__ __forceinline__ void gl_lds16(const float* g, float* l) {
    __builtin_amdgcn_global_load_lds(
        (const __attribute__((address_space(1))) unsigned int*)g,
        (__attribute__((address_space(3))) unsigned int*)l,
        16, 0, 0);
}

__global__ __launch_bounds__(256) void policy_kernel(
    const int*   __restrict__ e,
    const int*   __restrict__ q,
    const float* __restrict__ H,
    const int*   __restrict__ r_space,
    const float* __restrict__ r_mask,
    const float* __restrict__ entity_emb,
    const float* __restrict__ rel_emb,
    const float* __restrict__ W1,
    const float* __restrict__ b1,
    const float* __restrict__ W2,
    const float* __restrict__ b2,
    float* __restrict__ dist_out,
    float* __restrict__ ent_out)
{
    const int t    = threadIdx.x;          // 0..255
    const int lane = t & 63;
    const int wv_id = t >> 6;              // wave 0..3
    const int b0   = blockIdx.x * BB;

    __shared__ __align__(16) float xinT[DIN][BB];       // 8 KB, transposed input
    __shared__ __align__(16) float wbuf[2][KT * ACT];   // 64 KB, W double buffer
    __shared__ __align__(16) float hmidT[ACT][BB];      // 4 KB, transposed hidden
    __shared__ __align__(16) float x2s[BB][DR];         // 2 KB
    __shared__ float wredM[4][BB], wredS[4][BB], wredL[4][BB];

    // ---------- early loads: action space, masks, biases ---------------------
    int   ridx[BB];
    float msk[BB];
    #pragma unroll
    for (int bb = 0; bb < BB; ++bb) {
        ridx[bb] = r_space[(b0 + bb) * AA + t];
        msk[bb]  = r_mask [(b0 + bb) * AA + t];
    }
    const float bias1 = b1[t];
    const float bias2 = b2[t & (DR - 1)];

    // ---------- stage X = concat(E[e], H, Q[q]) transposed into LDS ----------
    #pragma unroll
    for (int j = 0; j < (DIN * BB) / 256; ++j) {
        const int i  = t + j * 256;
        const int c  = i >> 2;             // column 0..511
        const int bb = i & 3;
        const int b  = b0 + bb;
        float v;
        if (c < DE)           v = entity_emb[e[b] * DE + c];
        else if (c < DE + DH) v = H[b * DH + (c - DE)];
        else                  v = rel_emb[q[b] * DR + (c - DE - DH)];
        xinT[c][bb] = v;
    }

    // ---------- stage W1 tile 0 (8 KB/wave? no: 8 calls x 1KB/wave) ----------
    {
        const float* g = W1;               // tile 0 is contiguous KT*ACT floats
        #pragma unroll
        for (int c = 0; c < 8; ++c) {
            const int chunk = c * 4 + wv_id;           // 32 chunks of 256 floats
            gl_lds16(g + chunk * 256 + lane * 4, &wbuf[0][chunk * 256]);
        }
    }
    __syncthreads();   // publishes xinT (also drains tile-0 stage; prologue only)

    // ---------- layer 1: h = relu(X @ W1 + b1); thread t owns column t -------
    float a0 = bias1, a1 = bias1, a2 = bias1, a3 = bias1;
    const float4* xv = (const float4*)&xinT[0][0];      // xv[k] = 4 rows at col k
    for (int tt = 0; tt < NT1; ++tt) {
        const int cur = tt & 1;
        if (tt + 1 < NT1) {
            const float* g = W1 + (tt + 1) * KT * ACT;
            #pragma unroll
            for (int c = 0; c < 8; ++c) {
                const int chunk = c * 4 + wv_id;
                gl_lds16(g + chunk * 256 + lane * 4, &wbuf[cur ^ 1][chunk * 256]);
            }
            asm volatile("s_waitcnt vmcnt(8)" ::: "memory");  // tile tt landed
        } else {
            asm volatile("s_waitcnt vmcnt(0)" ::: "memory");
        }
        __builtin_amdgcn_s_barrier();
        const float* wl = &wbuf[cur][t];
        #pragma unroll
        for (int kk = 0; kk < KT; ++kk) {
            const float  wvv = wl[kk * ACT];            // lanes consecutive: conflict-free
            const float4 x4  = xv[tt * KT + kk];        // broadcast
            a0 = fmaf(x4.x, wvv, a0);
            a1 = fmaf(x4.y, wvv, a1);
            a2 = fmaf(x4.z, wvv, a2);
            a3 = fmaf(x4.w, wvv, a3);
        }
        asm volatile("s_waitcnt lgkmcnt(0)" ::: "memory");    // my reads done
        __builtin_amdgcn_s_barrier();                          // safe to overwrite
    }

    {
        float4 hv;
        hv.x = fmaxf(a0, 0.f); hv.y = fmaxf(a1, 0.f);
        hv.z = fmaxf(a2, 0.f); hv.w = fmaxf(a3, 0.f);
        ((float4*)&hmidT[0][0])[t] = hv;
    }
    // stage W2 tile 0 into wbuf[0] (tile = KT*DR = 4096 floats = 16 chunks)
    {
        const float* g = W2;
        #pragma unroll
        for (int c = 0; c < 4; ++c) {
            const int chunk = c * 4 + wv_id;
            gl_lds16(g + chunk * 256 + lane * 4, &wbuf[0][chunk * 256]);
        }
    }
    __syncthreads();   // publishes hmidT (drains W2 tile-0 stage; boundary only)

    // ---------- layer 2: x2 = h @ W2 + b2 ------------------------------------
    const int jj    = t & (DR - 1);
    const int gHalf = t >> 7;
    float c0 = bias2, c1 = bias2;
    const float4* hv4 = (const float4*)&hmidT[0][0];
    for (int tt = 0; tt < NT2; ++tt) {
        const int cur = tt & 1;
        if (tt + 1 < NT2) {
            const float* g = W2 + (tt + 1) * KT * DR;
            #pragma unroll
            for (int c = 0; c < 4; ++c) {
                const int chunk = c * 4 + wv_id;
                gl_lds16(g + chunk * 256 + lane * 4, &wbuf[cur ^ 1][chunk * 256]);
            }
            asm volatile("s_waitcnt vmcnt(4)" ::: "memory");
        } else {
            asm volatile("s_waitcnt vmcnt(0)" ::: "memory");
        }
        __builtin_amdgcn_s_barrier();
        const float* wl = &wbuf[cur][jj];
        #pragma unroll
        for (int kk = 0; kk < KT; ++kk) {
            const float  wvv = wl[kk * DR];
            const float4 hk  = hv4[tt * KT + kk];       // broadcast
            const float  h0  = gHalf ? hk.z : hk.x;
            const float  h1  = gHalf ? hk.w : hk.y;
            c0 = fmaf(h0, wvv, c0);
            c1 = fmaf(h1, wvv, c1);
        }
        asm volatile("s_waitcnt lgkmcnt(0)" ::: "memory");
        __builtin_amdgcn_s_barrier();
    }
    x2s[2 * gHalf + 0][jj] = c0;
    x2s[2 * gHalf + 1][jj] = c1;
    __syncthreads();

    // ---------- logits: thread t = action t, rows bb = 0..3 ------------------
    float lg[BB];
    #pragma unroll
    for (int bb = 0; bb < BB; ++bb) {
        const float4* rr = (const float4*)(rel_emb + (size_t)ridx[bb] * DR);
        const float4* xx = (const float4*)&x2s[bb][0];
        float s = 0.f;
        #pragma unroll
        for (int d = 0; d < DR / 4; ++d) {
            const float4 rv = rr[d];
            const float4 x4 = xx[d];
            s = fmaf(rv.x, x4.x, s);
            s = fmaf(rv.y, x4.y, s);
            s = fmaf(rv.z, x4.z, s);
            s = fmaf(rv.w, x4.w, s);
        }
        lg[bb] = s - (1.0f - msk[bb]) * 1e31f;
    }

    // ---------- block-wide max per row ---------------------------------------
    float m[BB];
    #pragma unroll
    for (int bb = 0; bb < BB; ++bb) m[bb] = lg[bb];
    #pragma unroll
    for (int off = 32; off >= 1; off >>= 1) {
        #pragma unroll
        for (int bb = 0; bb < BB; ++bb)
            m[bb] = fmaxf(m[bb], __shfl_xor(m[bb], off, 64));
    }
    if (lane == 0) {
        #pragma unroll
        for (int bb = 0; bb < BB; ++bb) wredM[wv_id][bb] = m[bb];
    }
    __syncthreads();
    #pragma unroll
    for (int bb = 0; bb < BB; ++bb)
        m[bb] = fmaxf(fmaxf(wredM[0][bb], wredM[1][bb]),
                      fmaxf(wredM[2][bb], wredM[3][bb]));

    // ---------- exp; joint reduce of S = sum p and SL = sum p*(lg-m) ---------
    float p[BB], s[BB], sl[BB];
    #pragma unroll
    for (int bb = 0; bb < BB; ++bb) {
        p[bb]  = __expf(lg[bb] - m[bb]);
        s[bb]  = p[bb];
        sl[bb] = p[bb] * (lg[bb] - m[bb]);
    }
    #pragma unroll
    for (int off = 32; off >= 1; off >>= 1) {
        #pragma unroll
        for (int bb = 0; bb < BB; ++bb) {
            s[bb]  += __shfl_xor(s[bb],  off, 64);
            sl[bb] += __shfl_xor(sl[bb], off, 64);
        }
    }
    if (lane == 0) {
        #pragma unroll
        for (int bb = 0; bb < BB; ++bb) { wredS[wv_id][bb] = s[bb]; wredL[wv_id][bb] = sl[bb]; }
    }
    __syncthreads();
    float S[BB], SL[BB];
    #pragma unroll
    for (int bb = 0; bb < BB; ++bb) {
        S[bb]  = wredS[0][bb] + wredS[1][bb] + wredS[2][bb] + wredS[3][bb];
        SL[bb] = wredL[0][bb] + wredL[1][bb] + wredL[2][bb] + wredL[3][bb];
    }

    // ---------- dist + entropy ------------------------------------------------
    #pragma unroll
    for (int bb = 0; bb < BB; ++bb) {
        const float inv = 1.0f / S[bb];
        dist_out[(b0 + bb) * AA + t] = p[bb] * inv;
    }
    if (t == 0) {
        #pragma unroll
        for (int bb = 0; bb < BB; ++bb)
            ent_out[b0 + bb] = __logf(S[bb]) - SL[bb] / S[bb];
    }
}

extern "C" void kernel_launch(void* const* d_in, const int* in_sizes, int n_in,
                              void* d_out, int out_size, void* d_ws, size_t ws_size,
                              hipStream_t stream) {
    const int*   e          = (const int*)  d_in[0];
    const int*   q          = (const int*)  d_in[1];
    const float* H          = (const float*)d_in[2];
    const int*   r_space    = (const int*)  d_in[3];
    const float* r_mask     = (const float*)d_in[4];
    const float* entity_emb = (const float*)d_in[5];
    const float* rel_emb    = (const float*)d_in[6];
    const float* W1         = (const float*)d_in[7];
    const float* b1         = (const float*)d_in[8];
    const float* W2         = (const float*)d_in[9];
    const float* b2         = (const float*)d_in[10];

    const int B = in_sizes[0];              // 2048
    float* dist_out = (float*)d_out;        // [B, 256]
    float* ent_out  = (float*)d_out + (size_t)B * AA;  // [B]

    policy_kernel<<<B / BB, 256, 0, stream>>>(
        e, q, H, r_space, r_mask, entity_emb, rel_emb,
        W1, b1, W2, b2, dist_out, ent_out);
}